// Round 12
// baseline (2424.246 us; speedup 1.0000x reference)
//
#include <hip/hip_runtime.h>

// ---------------------------------------------------------------------------
// RAFT+DICL correlation module — fp16 MFMA implicit-GEMM, v6.
//  v5 + occupancy/latency fixes:
//   - NTW=2 oc-tiles per wave (acc=32 VGPR) -> ~7 waves/SIMD, 2x blocks
//   - level fusion: 648-image batched dispatches (lvl = g/162 per block)
// Input order INTERLEAVED: d_in[0]=fmap1_0, d_in[1]=fmap2_0, ...
// ---------------------------------------------------------------------------

typedef _Float16 half_t;
typedef _Float16 f16x8 __attribute__((ext_vector_type(8)));
typedef float f32x4 __attribute__((ext_vector_type(4)));

constexpr int D9 = 9, NB = 2, HH = 48, WW = 64;
constexpr int NIMG = NB * D9 * D9;   // 162 per level
constexpr int NTOT = 4 * NIMG;       // 648 across levels
constexpr int HW = HH * WW;          // 3072
constexpr int H2 = 24, W2 = 32, HW2 = H2 * W2;

constexpr int F1S = 9 * 1 * 6 * 512;
constexpr int F2S = 9 * 3 * 8 * 512;
constexpr int F3S = 9 * 4 * 8 * 512;
constexpr int F4S = 9 * 4 * 4 * 512;
constexpr int F5S = 4 * 4 * 2 * 2 * 512;
constexpr int KT1 = 576, WT1L = KT1 * 96;

static inline int cdiv(int a, int b) { return (a + b - 1) / b; }

__device__ __forceinline__ int xcd_swz(int b, int nb)
{
    int q = nb >> 3, r = nb & 7;
    int x = b & 7, j = b >> 3;
    return (x < r) ? (x * (q + 1) + j) : (r + x * q + j);
}

// ---------------- weight prep ----------------
__global__ void transpose_w(const float* __restrict__ w, float* __restrict__ wT,
                            int OC, int K, int dstStride)
{
    int idx = blockIdx.x * blockDim.x + threadIdx.x;
    int tot = 4 * OC * K;
    if (idx >= tot) return;
    int lvl = idx / (OC * K);
    int r = idx - lvl * OC * K;
    int oc = r / K;
    int k = r - oc * K;
    wT[(size_t)lvl * dstStride + (size_t)k * OC + oc] = w[idx];
}

template <int OC, int ICSRC, int ICBASE, int ICS>
__global__ void prep3(const float* __restrict__ w, half_t* __restrict__ dst)
{
    constexpr int NT = OC / 16;
    constexpr int LS = 9 * ICS * NT * 512;
    int idx = blockIdx.x * blockDim.x + threadIdx.x;
    if (idx >= 4 * LS) return;
    int j = idx & 7, l = (idx >> 3) & 63;
    int r = idx >> 9;
    int tile = r % NT; r /= NT;
    int s = r % ICS;  r /= ICS;
    int t = r % 9;    r /= 9;
    int lvl = r;
    int ic = ICBASE + s * 32 + (l >> 4) * 8 + j;
    int oc = tile * 16 + (l & 15);
    float v = w[(size_t)lvl * OC * ICSRC * 9 + ((size_t)oc * ICSRC + ic) * 9 + t];
    dst[(size_t)lvl * LS + (((t * ICS + s) * NT + tile) << 9) + l * 8 + j] = (half_t)v;
}

__global__ void prep5(const float* __restrict__ w, half_t* __restrict__ dst)
{
    constexpr int LS = F5S;
    int idx = blockIdx.x * blockDim.x + threadIdx.x;
    if (idx >= 4 * LS) return;
    int j = idx & 7, l = (idx >> 3) & 63;
    int r = idx >> 9;
    int tile = r & 1; r >>= 1;
    int s = r & 1;    r >>= 1;
    int uv = r & 3;   r >>= 2;
    int cls = r & 3;  r >>= 2;
    int lvl = r;
    int u = uv >> 1, v = uv & 1, p = cls >> 1, q = cls & 1;
    int ky = p + 2 * u, kx = q + 2 * v;
    int ic = s * 32 + (l >> 4) * 8 + j;
    int oc = tile * 16 + (l & 15);
    float val = w[(size_t)lvl * 32 * 64 * 16 + ((size_t)oc * 64 + ic) * 16 + ky * 4 + kx];
    dst[(size_t)lvl * LS + (((cls * 8 + uv * 2 + s) * 2 + tile) << 9) + l * 8 + j] = (half_t)val;
}

// ---------------- conv1 f1-half (fp32, NHWC fp32 out), 8 (lvl,b) images -----
__global__ __launch_bounds__(256)
void conv_part(const float* __restrict__ f1_0, const float* __restrict__ f1_1,
               const float* __restrict__ f1_2, const float* __restrict__ f1_3,
               const float* __restrict__ wT1, const float* __restrict__ mb1,
               float* __restrict__ part)
{
    constexpr int TO = 16, IC = 32, OC = 96;
    int z = blockIdx.z;             // lvl*2 + b
    int lvl = z >> 1, b = z & 1;
    const float* in = (lvl == 0 ? f1_0 : lvl == 1 ? f1_1 : lvl == 2 ? f1_2 : f1_3)
                      + (size_t)b * IC * HW;
    const float* wT = wT1 + (size_t)lvl * WT1L;
    const float* bias = mb1 + lvl * 96;

    int tx = threadIdx.x;
    int ox = tx % WW;
    int oy = blockIdx.x * 4 + tx / WW;
    int oc0 = blockIdx.y * TO;

    float acc[TO];
    #pragma unroll
    for (int o = 0; o < TO; ++o) acc[o] = bias[oc0 + o];
    bool mL = ox >= 1, mR = ox + 1 < WW;
    int xl = mL ? ox - 1 : 0, xr = mR ? ox + 1 : WW - 1;
    const float* wk = wT + oc0;
    for (int ic = 0; ic < IC; ++ic) {
        const float* icp = in + ic * HW;
        const float* wpk = wk + ic * 9 * OC;
        #pragma unroll
        for (int ky = 0; ky < 3; ++ky) {
            int iy = oy + ky - 1;
            if ((unsigned)iy < (unsigned)HH) {
                const float* rp = icp + iy * WW;
                float v0 = rp[xl]; v0 = mL ? v0 : 0.f;
                float v1 = rp[ox];
                float v2 = rp[xr]; v2 = mR ? v2 : 0.f;
                const float* wp = wpk + ky * 3 * OC;
                #pragma unroll
                for (int o = 0; o < TO; ++o) acc[o] = fmaf(v0, wp[o], acc[o]);
                #pragma unroll
                for (int o = 0; o < TO; ++o) acc[o] = fmaf(v1, wp[OC + o], acc[o]);
                #pragma unroll
                for (int o = 0; o < TO; ++o) acc[o] = fmaf(v2, wp[2 * OC + o], acc[o]);
            }
        }
    }
    float* ob = part + ((size_t)z * HW + oy * WW + ox) * OC + oc0;
    #pragma unroll
    for (int o = 0; o < TO; ++o) ob[o] = acc[o];
}

// ---------------- sampling -> corr NHWC fp16 (level-batched) ----------------
__global__ void sample_kernel(const float* __restrict__ f2_0, const float* __restrict__ f2_1,
                              const float* __restrict__ f2_2, const float* __restrict__ f2_3,
                              const float* __restrict__ coords, half_t* __restrict__ corr,
                              int n0, int nimg)
{
    int idx = blockIdx.x * blockDim.x + threadIdx.x;
    if (idx >= nimg * HW) return;
    int x = idx % WW;
    int t = idx / WW;
    int y = t % HH;
    int nl = t / HH;
    int g = n0 + nl;                 // 0..647
    int lvl = g / NIMG;
    int i = g - lvl * NIMG;
    int b = i / 81;
    int c81 = i - b * 81;
    int di = c81 / D9, dj = c81 % D9;
    const float* f2 = (lvl == 0 ? f2_0 : lvl == 1 ? f2_1 : lvl == 2 ? f2_2 : f2_3);
    int h2 = HH >> lvl, w2 = WW >> lvl;
    float inv_scale = 1.0f / (float)(1 << lvl);

    float cx = coords[((size_t)(b * 2 + 0) * HH + y) * WW + x];
    float cy = coords[((size_t)(b * 2 + 1) * HH + y) * WW + x];
    float gx = cx * inv_scale + (float)(di - 4);
    float gy = cy * inv_scale + (float)(dj - 4);
    float x0f = floorf(gx), y0f = floorf(gy);
    float wx = gx - x0f, wy = gy - y0f;
    int x0 = (int)x0f, y0 = (int)y0f;
    int x1 = x0 + 1, y1 = y0 + 1;
    bool vx0 = (x0 >= 0) && (x0 <= w2 - 1), vx1 = (x1 >= 0) && (x1 <= w2 - 1);
    bool vy0 = (y0 >= 0) && (y0 <= h2 - 1), vy1 = (y1 >= 0) && (y1 <= h2 - 1);
    int xc0 = min(max(x0, 0), w2 - 1), xc1 = min(max(x1, 0), w2 - 1);
    int yc0 = min(max(y0, 0), h2 - 1), yc1 = min(max(y1, 0), h2 - 1);
    float m00 = (vx0 && vy0) ? (1.f - wx) * (1.f - wy) : 0.f;
    float m10 = (vx1 && vy0) ? wx * (1.f - wy) : 0.f;
    float m01 = (vx0 && vy1) ? (1.f - wx) * wy : 0.f;
    float m11 = (vx1 && vy1) ? wx * wy : 0.f;

    const float* f2b = f2 + (size_t)b * 32 * h2 * w2;
    half_t* outb = corr + ((size_t)nl * HW + y * WW + x) * 32;
    int o00 = yc0 * w2 + xc0, o10 = yc0 * w2 + xc1;
    int o01 = yc1 * w2 + xc0, o11 = yc1 * w2 + xc1;
    #pragma unroll 8
    for (int ch = 0; ch < 32; ++ch) {
        const float* im = f2b + (size_t)ch * h2 * w2;
        float v = m00 * im[o00] + m10 * im[o10] + m01 * im[o01] + m11 * im[o11];
        outb[ch] = (half_t)v;
    }
}

// ---------------- MFMA 3x3 conv (NHWC fp16), level-batched, NTW tiles -------
template <int ICS, int ICT, int OC, int IH, int IW, int OH, int OW, int S, bool PARTI, int NTW>
__global__ __launch_bounds__(256)
void conv_mfma(const half_t* __restrict__ in, const half_t* __restrict__ fragBase, int FS,
               const float* __restrict__ biasBase, half_t* __restrict__ out,
               const float* __restrict__ part, int n0, int gx, int gxy, int nb)
{
    constexpr int NT = OC / 16;
    int lb = xcd_swz(blockIdx.x, nb);
    int n = lb / gxy;                      // chunk-local image
    int rem = lb - n * gxy;
    int ty = rem / gx;
    int tx = rem - ty * gx;
    int g = n0 + n;
    int lvl = g / NIMG;
    const half_t* wfrag = fragBase + (size_t)lvl * FS;
    const float* bias = biasBase + lvl * OC;

    int lane = threadIdx.x & 63;
    int wv = threadIdx.x >> 6;
    int tile0 = ty * NTW;
    int pt0 = tx * 16 + wv * 4;
    int colc = lane & 15;
    int kg = lane >> 4;

    const half_t* inn = in + (size_t)n * IH * IW * ICT;

    int px[4], py[4];
    #pragma unroll
    for (int m = 0; m < 4; ++m) {
        int p = (pt0 + m) * 16 + colc;
        px[m] = p % OW;
        py[m] = p / OW;
    }

    f32x4 acc[4][NTW];
    if (PARTI) {
        int i = g - lvl * NIMG;
        int pimg = lvl * 2 + i / 81;
        const float* pp = part + (size_t)pimg * OH * OW * 96;
        #pragma unroll
        for (int m = 0; m < 4; ++m)
            #pragma unroll
            for (int nn = 0; nn < NTW; ++nn)
                #pragma unroll
                for (int j = 0; j < 4; ++j)
                    acc[m][nn][j] = pp[(size_t)((pt0 + m) * 16 + kg * 4 + j) * 96
                                       + (tile0 + nn) * 16 + colc];
    } else {
        #pragma unroll
        for (int nn = 0; nn < NTW; ++nn) {
            float bv = bias[(tile0 + nn) * 16 + colc];
            #pragma unroll
            for (int m = 0; m < 4; ++m)
                #pragma unroll
                for (int j = 0; j < 4; ++j) acc[m][nn][j] = bv;
        }
    }

    f16x8 zz = {};
    #pragma unroll
    for (int t = 0; t < 9; ++t) {
        int dy = t / 3 - 1, dx = t % 3 - 1;
        const half_t* ap[4];
        bool av[4];
        #pragma unroll
        for (int m = 0; m < 4; ++m) {
            int sx = px[m] * S + dx, sy = py[m] * S + dy;
            av[m] = ((unsigned)sx < (unsigned)IW) && ((unsigned)sy < (unsigned)IH);
            int sxc = min(max(sx, 0), IW - 1), syc = min(max(sy, 0), IH - 1);
            ap[m] = inn + ((size_t)syc * IW + sxc) * ICT + kg * 8;
        }
        #pragma unroll
        for (int s = 0; s < ICS; ++s) {
            f16x8 bv[NTW];
            #pragma unroll
            for (int nn = 0; nn < NTW; ++nn)
                bv[nn] = *(const f16x8*)(wfrag + (((t * ICS + s) * NT + tile0 + nn) << 9) + lane * 8);
            #pragma unroll
            for (int m = 0; m < 4; ++m) {
                f16x8 a = *(const f16x8*)(ap[m] + s * 32);
                a = av[m] ? a : zz;
                #pragma unroll
                for (int nn = 0; nn < NTW; ++nn)
                    acc[m][nn] = __builtin_amdgcn_mfma_f32_16x16x32_f16(a, bv[nn], acc[m][nn], 0, 0, 0);
            }
        }
    }

    #pragma unroll
    for (int m = 0; m < 4; ++m)
        #pragma unroll
        for (int nn = 0; nn < NTW; ++nn)
            #pragma unroll
            for (int j = 0; j < 4; ++j) {
                float r = fmaxf(acc[m][nn][j], 0.f);
                int p = (pt0 + m) * 16 + kg * 4 + j;
                out[((size_t)n * OH * OW + p) * OC + (tile0 + nn) * 16 + colc] = (half_t)r;
            }
}

// ---------------- MFMA deconv (4 parity classes), level-batched -------------
__global__ __launch_bounds__(256)
void deconv_mfma(const half_t* __restrict__ in, const half_t* __restrict__ fragBase,
                 const float* __restrict__ mb5, half_t* __restrict__ out, int n0, int nb)
{
    int lb = xcd_swz(blockIdx.x, nb);
    int n = lb / 12;
    int rem = lb - n * 12;
    int cls = rem / 3;
    int tx = rem - cls * 3;
    int g = n0 + n;
    int lvl = g / NIMG;
    const half_t* wfrag = fragBase + (size_t)lvl * F5S;
    const float* bias = mb5 + lvl * 32;

    int lane = threadIdx.x & 63;
    int wv = threadIdx.x >> 6;
    int p = cls >> 1, q = cls & 1;
    int pt0 = tx * 16 + wv * 4;
    int colc = lane & 15, kg = lane >> 4;
    const half_t* inn = in + (size_t)n * HW2 * 64;

    int pa[4], pb[4];
    #pragma unroll
    for (int m = 0; m < 4; ++m) {
        int pos = (pt0 + m) * 16 + colc;
        pa[m] = pos >> 5;
        pb[m] = pos & 31;
    }

    f32x4 acc[4][2];
    float b0 = bias[colc], b1 = bias[16 + colc];
    #pragma unroll
    for (int m = 0; m < 4; ++m)
        #pragma unroll
        for (int j = 0; j < 4; ++j) { acc[m][0][j] = b0; acc[m][1][j] = b1; }

    f16x8 zz = {};
    #pragma unroll
    for (int uv = 0; uv < 4; ++uv) {
        int u = uv >> 1, v = uv & 1;
        const half_t* ap[4];
        bool av[4];
        #pragma unroll
        for (int m = 0; m < 4; ++m) {
            int sy = pa[m] + p - 1 + u, sx = pb[m] + q - 1 + v;
            av[m] = ((unsigned)sx < (unsigned)W2) && ((unsigned)sy < (unsigned)H2);
            int sxc = min(max(sx, 0), W2 - 1), syc = min(max(sy, 0), H2 - 1);
            ap[m] = inn + ((size_t)syc * W2 + sxc) * 64 + kg * 8;
        }
        #pragma unroll
        for (int s = 0; s < 2; ++s) {
            f16x8 b0v = *(const f16x8*)(wfrag + (((cls * 8 + uv * 2 + s) * 2 + 0) << 9) + lane * 8);
            f16x8 b1v = *(const f16x8*)(wfrag + (((cls * 8 + uv * 2 + s) * 2 + 1) << 9) + lane * 8);
            #pragma unroll
            for (int m = 0; m < 4; ++m) {
                f16x8 a = *(const f16x8*)(ap[m] + s * 32);
                a = av[m] ? a : zz;
                acc[m][0] = __builtin_amdgcn_mfma_f32_16x16x32_f16(a, b0v, acc[m][0], 0, 0, 0);
                acc[m][1] = __builtin_amdgcn_mfma_f32_16x16x32_f16(a, b1v, acc[m][1], 0, 0, 0);
            }
        }
    }

    #pragma unroll
    for (int m = 0; m < 4; ++m)
        #pragma unroll
        for (int nn = 0; nn < 2; ++nn)
            #pragma unroll
            for (int j = 0; j < 4; ++j) {
                int pos = (pt0 + m) * 16 + kg * 4 + j;
                int a2 = pos >> 5, b2 = pos & 31;
                int oy = 2 * a2 + p, ox = 2 * b2 + q;
                float r = fmaxf(acc[m][nn][j], 0.f);
                out[((size_t)n * HW + oy * WW + ox) * 32 + nn * 16 + colc] = (half_t)r;
            }
}

// ---------------- conv6 (32->1), level-batched ----------------
__global__ void conv6_kernel(const half_t* __restrict__ in, const float* __restrict__ mw6,
                             const float* __restrict__ mb6, float* __restrict__ cost,
                             int n0, int nimg)
{
    int idx = blockIdx.x * blockDim.x + threadIdx.x;
    if (idx >= nimg * HW) return;
    int x = idx % WW;
    int t = idx / WW;
    int y = t % HH;
    int nl = t / HH;
    int g = n0 + nl;
    int lvl = g / NIMG;
    const float* w6 = mw6 + (size_t)lvl * 288;
    float acc = mb6[lvl];
    const half_t* ib = in + (size_t)nl * HW * 32;
    #pragma unroll
    for (int tap = 0; tap < 9; ++tap) {
        int sy = y + tap / 3 - 1, sx = x + tap % 3 - 1;
        if ((unsigned)sy < (unsigned)HH && (unsigned)sx < (unsigned)WW) {
            const f16x8* pp = (const f16x8*)(ib + ((size_t)sy * WW + sx) * 32);
            #pragma unroll
            for (int c8 = 0; c8 < 4; ++c8) {
                f16x8 v = pp[c8];
                #pragma unroll
                for (int j = 0; j < 8; ++j)
                    acc = fmaf((float)v[j], w6[(c8 * 8 + j) * 9 + tap], acc);
            }
        }
    }
    cost[(size_t)g * HW + y * WW + x] = acc;
}

// ---------------- DAP (all levels, one launch) ----------------
__global__ void dap_kernel(const float* __restrict__ cost, const float* __restrict__ dapw,
                           float* __restrict__ out)
{
    int idx = blockIdx.x * blockDim.x + threadIdx.x;
    if (idx >= 4 * NB * 81 * HW) return;
    int px = idx % HW;
    int t = idx / HW;
    int o = t % 81;
    t /= 81;
    int b = t & 1;
    int lvl = t >> 1;
    const float* dw = dapw + (size_t)lvl * 6561 + (size_t)o * 81;
    const float* cb = cost + ((size_t)lvl * NIMG + b * 81) * HW + px;
    float acc = 0.f;
    #pragma unroll 9
    for (int c = 0; c < 81; ++c) acc = fmaf(dw[c], cb[(size_t)c * HW], acc);
    out[((size_t)(b * 324 + lvl * 81 + o)) * HW + px] = acc;
}

// ---------------------------------------------------------------------------
extern "C" void kernel_launch(void* const* d_in, const int* in_sizes, int n_in,
                              void* d_out, int out_size, void* d_ws, size_t ws_size,
                              hipStream_t stream)
{
    const float* f1_0 = (const float*)d_in[0];
    const float* f2_0 = (const float*)d_in[1];
    const float* f1_1 = (const float*)d_in[2];
    const float* f2_1 = (const float*)d_in[3];
    const float* f1_2 = (const float*)d_in[4];
    const float* f2_2 = (const float*)d_in[5];
    const float* f1_3 = (const float*)d_in[6];
    const float* f2_3 = (const float*)d_in[7];
    const float* coords = (const float*)d_in[8];
    const float* mw1 = (const float*)d_in[9];
    const float* mb1 = (const float*)d_in[10];
    const float* mw2 = (const float*)d_in[11];
    const float* mb2 = (const float*)d_in[12];
    const float* mw3 = (const float*)d_in[13];
    const float* mb3 = (const float*)d_in[14];
    const float* mw4 = (const float*)d_in[15];
    const float* mb4 = (const float*)d_in[16];
    const float* mw5 = (const float*)d_in[17];
    const float* mb5 = (const float*)d_in[18];
    const float* mw6 = (const float*)d_in[19];
    const float* mb6 = (const float*)d_in[20];
    const float* dapw = (const float*)d_in[21];
    float* out = (float*)d_out;

    auto al = [](size_t x) { return (x + 255) / 256 * 256; };
    const size_t wT1B = al((size_t)4 * WT1L * 4);
    const size_t fragB = al((size_t)4 * (F1S + F2S + F3S + F4S + F5S) * 2);
    const size_t partB = al((size_t)8 * HW * 96 * 4);
    const size_t costB = al((size_t)NTOT * HW * 4);
    const size_t SA = (size_t)HW * 32 * 2;
    const size_t SB = (size_t)HW * 96 * 2;

    static const int divs[12] = {648, 324, 216, 162, 108, 81, 54, 36, 27, 18, 9, 1};
    int chunk = 1;
    for (int i = 0; i < 12; ++i) {
        size_t need = wT1B + fragB + partB + costB + (size_t)divs[i] * (SA + SB) + 1024;
        if (need <= ws_size) { chunk = divs[i]; break; }
    }

    char* wsb = (char*)d_ws;
    float* wT1 = (float*)wsb;
    half_t* frags = (half_t*)(wsb + wT1B);
    half_t* Fr1 = frags;
    half_t* Fr2 = Fr1 + (size_t)4 * F1S;
    half_t* Fr3 = Fr2 + (size_t)4 * F2S;
    half_t* Fr4 = Fr3 + (size_t)4 * F3S;
    half_t* Fr5 = Fr4 + (size_t)4 * F4S;
    float* part = (float*)(wsb + wT1B + fragB);
    float* cost = (float*)(wsb + wT1B + fragB + partB);
    half_t* bufA = (half_t*)(wsb + wT1B + fragB + partB + costB);
    half_t* bufB = (half_t*)(wsb + wT1B + fragB + partB + costB + (size_t)chunk * SA);

    const int TPB = 256;

    transpose_w<<<cdiv(4 * 96 * KT1, TPB), TPB, 0, stream>>>(mw1, wT1, 96, KT1, WT1L);
    prep3<96, 64, 32, 1><<<cdiv(4 * F1S, TPB), TPB, 0, stream>>>(mw1, Fr1);
    prep3<128, 96, 0, 3><<<cdiv(4 * F2S, TPB), TPB, 0, stream>>>(mw2, Fr2);
    prep3<128, 128, 0, 4><<<cdiv(4 * F3S, TPB), TPB, 0, stream>>>(mw3, Fr3);
    prep3<64, 128, 0, 4><<<cdiv(4 * F4S, TPB), TPB, 0, stream>>>(mw4, Fr4);
    prep5<<<cdiv(4 * F5S, TPB), TPB, 0, stream>>>(mw5, Fr5);

    // conv1 f1-half for all 8 (lvl, b) images
    conv_part<<<dim3(12, 6, 8), TPB, 0, stream>>>(f1_0, f1_1, f1_2, f1_3, wT1, mb1, part);

    for (int n0 = 0; n0 < NTOT; n0 += chunk) {
        int n = chunk;
        sample_kernel<<<cdiv(n * HW, TPB), TPB, 0, stream>>>(
            f2_0, f2_1, f2_2, f2_3, coords, bufA, n0, n);
        // conv1 sampled-half + part C-init, relu: A -> B  (NT=6, NTW=2, gy=3)
        { int gx = 12, gxy = 36, nb = gxy * n;
          conv_mfma<1, 32, 96, 48, 64, 48, 64, 1, true, 2><<<nb, TPB, 0, stream>>>(
              bufA, Fr1, F1S, mb1, bufB, part, n0, gx, gxy, nb); }
        // conv2 96->128 s2 relu: B -> A  (NT=8, NTW=2, gy=4)
        { int gx = 3, gxy = 12, nb = gxy * n;
          conv_mfma<3, 96, 128, 48, 64, 24, 32, 2, false, 2><<<nb, TPB, 0, stream>>>(
              bufB, Fr2, F2S, mb2, bufA, nullptr, n0, gx, gxy, nb); }
        // conv3 128->128 relu: A -> B  (NT=8, NTW=2, gy=4)
        { int gx = 3, gxy = 12, nb = gxy * n;
          conv_mfma<4, 128, 128, 24, 32, 24, 32, 1, false, 2><<<nb, TPB, 0, stream>>>(
              bufA, Fr3, F3S, mb3, bufB, nullptr, n0, gx, gxy, nb); }
        // conv4 128->64 relu: B -> A  (NT=4, NTW=2, gy=2)
        { int gx = 3, gxy = 6, nb = gxy * n;
          conv_mfma<4, 128, 64, 24, 32, 24, 32, 1, false, 2><<<nb, TPB, 0, stream>>>(
              bufB, Fr4, F4S, mb4, bufA, nullptr, n0, gx, gxy, nb); }
        // deconv 64->32 relu: A -> B
        { int nb = 12 * n;
          deconv_mfma<<<nb, TPB, 0, stream>>>(bufA, Fr5, mb5, bufB, n0, nb); }
        // conv6 32->1: B -> cost
        conv6_kernel<<<cdiv(n * HW, TPB), TPB, 0, stream>>>(bufB, mw6, mb6, cost, n0, n);
    }
    dap_kernel<<<cdiv(4 * NB * 81 * HW, TPB), TPB, 0, stream>>>(cost, dapw, out);
}

// Round 13
// 1854.141 us; speedup vs baseline: 1.3075x; 1.3075x over previous
//
#include <hip/hip_runtime.h>

// ---------------------------------------------------------------------------
// RAFT+DICL correlation module — fp16 MFMA implicit-GEMM, v7.
//  = v5 (per-level, NTW=3/4, XCD swizzle; 1.91ms measured) + software-
//    pipelined conv_mfma inner loop: loads for step u+1 issued before the
//    MFMAs of step u (1-step lookahead double-buffer in registers).
// Input order INTERLEAVED: d_in[0]=fmap1_0, d_in[1]=fmap2_0, ...
// ---------------------------------------------------------------------------

typedef _Float16 half_t;
typedef _Float16 f16x8 __attribute__((ext_vector_type(8)));
typedef float f32x4 __attribute__((ext_vector_type(4)));

constexpr int D9 = 9, NB = 2, HH = 48, WW = 64;
constexpr int NIMG = NB * D9 * D9;   // 162
constexpr int HW = HH * WW;          // 3072
constexpr int H2 = 24, W2 = 32, HW2 = H2 * W2;

constexpr int F1S = 9 * 1 * 6 * 512;
constexpr int F2S = 9 * 3 * 8 * 512;
constexpr int F3S = 9 * 4 * 8 * 512;
constexpr int F4S = 9 * 4 * 4 * 512;
constexpr int F5S = 4 * 4 * 2 * 2 * 512;
constexpr int KT1 = 576, WT1L = KT1 * 96;

static inline int cdiv(int a, int b) { return (a + b - 1) / b; }

__device__ __forceinline__ int xcd_swz(int b, int nb)
{
    int q = nb >> 3, r = nb & 7;
    int x = b & 7, j = b >> 3;
    return (x < r) ? (x * (q + 1) + j) : (r + x * q + j);
}

// ---------------- weight prep ----------------
__global__ void transpose_w(const float* __restrict__ w, float* __restrict__ wT,
                            int OC, int K, int dstStride)
{
    int idx = blockIdx.x * blockDim.x + threadIdx.x;
    int tot = 4 * OC * K;
    if (idx >= tot) return;
    int lvl = idx / (OC * K);
    int r = idx - lvl * OC * K;
    int oc = r / K;
    int k = r - oc * K;
    wT[(size_t)lvl * dstStride + (size_t)k * OC + oc] = w[idx];
}

template <int OC, int ICSRC, int ICBASE, int ICS>
__global__ void prep3(const float* __restrict__ w, half_t* __restrict__ dst)
{
    constexpr int NT = OC / 16;
    constexpr int LS = 9 * ICS * NT * 512;
    int idx = blockIdx.x * blockDim.x + threadIdx.x;
    if (idx >= 4 * LS) return;
    int j = idx & 7, l = (idx >> 3) & 63;
    int r = idx >> 9;
    int tile = r % NT; r /= NT;
    int s = r % ICS;  r /= ICS;
    int t = r % 9;    r /= 9;
    int lvl = r;
    int ic = ICBASE + s * 32 + (l >> 4) * 8 + j;
    int oc = tile * 16 + (l & 15);
    float v = w[(size_t)lvl * OC * ICSRC * 9 + ((size_t)oc * ICSRC + ic) * 9 + t];
    dst[(size_t)lvl * LS + (((t * ICS + s) * NT + tile) << 9) + l * 8 + j] = (half_t)v;
}

__global__ void prep5(const float* __restrict__ w, half_t* __restrict__ dst)
{
    constexpr int LS = F5S;
    int idx = blockIdx.x * blockDim.x + threadIdx.x;
    if (idx >= 4 * LS) return;
    int j = idx & 7, l = (idx >> 3) & 63;
    int r = idx >> 9;
    int tile = r & 1; r >>= 1;
    int s = r & 1;    r >>= 1;
    int uv = r & 3;   r >>= 2;
    int cls = r & 3;  r >>= 2;
    int lvl = r;
    int u = uv >> 1, v = uv & 1, p = cls >> 1, q = cls & 1;
    int ky = p + 2 * u, kx = q + 2 * v;
    int ic = s * 32 + (l >> 4) * 8 + j;
    int oc = tile * 16 + (l & 15);
    float val = w[(size_t)lvl * 32 * 64 * 16 + ((size_t)oc * 64 + ic) * 16 + ky * 4 + kx];
    dst[(size_t)lvl * LS + (((cls * 8 + uv * 2 + s) * 2 + tile) << 9) + l * 8 + j] = (half_t)val;
}

// ---------------- conv1 f1-half (fp32, NHWC fp32 out), 2 images ----------------
__global__ __launch_bounds__(256)
void conv_part(const float* __restrict__ in, const float* __restrict__ wT,
               const float* __restrict__ bias, float* __restrict__ out)
{
    constexpr int TO = 16, IC = 32, OC = 96;
    int tx = threadIdx.x;
    int ox = tx % WW;
    int oy = blockIdx.x * 4 + tx / WW;
    int oc0 = blockIdx.y * TO;
    int n = blockIdx.z;

    float acc[TO];
    #pragma unroll
    for (int o = 0; o < TO; ++o) acc[o] = bias[oc0 + o];
    bool mL = ox >= 1, mR = ox + 1 < WW;
    int xl = mL ? ox - 1 : 0, xr = mR ? ox + 1 : WW - 1;
    const float* ip = in + (size_t)n * IC * HW;
    const float* wk = wT + oc0;
    for (int ic = 0; ic < IC; ++ic) {
        const float* icp = ip + ic * HW;
        const float* wpk = wk + ic * 9 * OC;
        #pragma unroll
        for (int ky = 0; ky < 3; ++ky) {
            int iy = oy + ky - 1;
            if ((unsigned)iy < (unsigned)HH) {
                const float* rp = icp + iy * WW;
                float v0 = rp[xl]; v0 = mL ? v0 : 0.f;
                float v1 = rp[ox];
                float v2 = rp[xr]; v2 = mR ? v2 : 0.f;
                const float* wp = wpk + ky * 3 * OC;
                #pragma unroll
                for (int o = 0; o < TO; ++o) acc[o] = fmaf(v0, wp[o], acc[o]);
                #pragma unroll
                for (int o = 0; o < TO; ++o) acc[o] = fmaf(v1, wp[OC + o], acc[o]);
                #pragma unroll
                for (int o = 0; o < TO; ++o) acc[o] = fmaf(v2, wp[2 * OC + o], acc[o]);
            }
        }
    }
    float* ob = out + ((size_t)n * HW + oy * WW + ox) * OC + oc0;
    #pragma unroll
    for (int o = 0; o < TO; ++o) ob[o] = acc[o];
}

// ---------------- sampling -> corr NHWC fp16 ----------------
__global__ void sample_kernel(const float* __restrict__ f2,
                              const float* __restrict__ coords, half_t* __restrict__ corr,
                              int n0, int nimg, int h2, int w2, float inv_scale)
{
    int idx = blockIdx.x * blockDim.x + threadIdx.x;
    if (idx >= nimg * HW) return;
    int x = idx % WW;
    int t = idx / WW;
    int y = t % HH;
    int nl = t / HH;
    int ng = n0 + nl;
    int b = ng / 81;
    int c81 = ng % 81;
    int di = c81 / D9, dj = c81 % D9;

    float cx = coords[((size_t)(b * 2 + 0) * HH + y) * WW + x];
    float cy = coords[((size_t)(b * 2 + 1) * HH + y) * WW + x];
    float gx = cx * inv_scale + (float)(di - 4);
    float gy = cy * inv_scale + (float)(dj - 4);
    float x0f = floorf(gx), y0f = floorf(gy);
    float wx = gx - x0f, wy = gy - y0f;
    int x0 = (int)x0f, y0 = (int)y0f;
    int x1 = x0 + 1, y1 = y0 + 1;
    bool vx0 = (x0 >= 0) && (x0 <= w2 - 1), vx1 = (x1 >= 0) && (x1 <= w2 - 1);
    bool vy0 = (y0 >= 0) && (y0 <= h2 - 1), vy1 = (y1 >= 0) && (y1 <= h2 - 1);
    int xc0 = min(max(x0, 0), w2 - 1), xc1 = min(max(x1, 0), w2 - 1);
    int yc0 = min(max(y0, 0), h2 - 1), yc1 = min(max(y1, 0), h2 - 1);
    float m00 = (vx0 && vy0) ? (1.f - wx) * (1.f - wy) : 0.f;
    float m10 = (vx1 && vy0) ? wx * (1.f - wy) : 0.f;
    float m01 = (vx0 && vy1) ? (1.f - wx) * wy : 0.f;
    float m11 = (vx1 && vy1) ? wx * wy : 0.f;

    const float* f2b = f2 + (size_t)b * 32 * h2 * w2;
    half_t* outb = corr + ((size_t)nl * HW + y * WW + x) * 32;
    int o00 = yc0 * w2 + xc0, o10 = yc0 * w2 + xc1;
    int o01 = yc1 * w2 + xc0, o11 = yc1 * w2 + xc1;
    #pragma unroll 8
    for (int ch = 0; ch < 32; ++ch) {
        const float* im = f2b + (size_t)ch * h2 * w2;
        float v = m00 * im[o00] + m10 * im[o10] + m01 * im[o01] + m11 * im[o11];
        outb[ch] = (half_t)v;
    }
}

// ---------------- MFMA 3x3 conv, software-pipelined (1-step lookahead) ------
template <int ICS, int ICT, int OC, int IH, int IW, int OH, int OW, int S, bool PARTI, int NTW>
__global__ __launch_bounds__(256)
void conv_mfma(const half_t* __restrict__ in, const half_t* __restrict__ wfrag,
               const float* __restrict__ bias, half_t* __restrict__ out,
               const float* __restrict__ part, int n0, int gx, int gxy, int nb)
{
    constexpr int NT = OC / 16;
    constexpr int NU = 9 * ICS;
    int lb = xcd_swz(blockIdx.x, nb);
    int n = lb / gxy;
    int rem = lb - n * gxy;
    int ty = rem / gx;
    int tx = rem - ty * gx;

    int lane = threadIdx.x & 63;
    int wv = threadIdx.x >> 6;
    int tile0 = ty * NTW;
    int pt0 = tx * 16 + wv * 4;
    int colc = lane & 15;
    int kg = lane >> 4;

    const half_t* inn = in + (size_t)n * IH * IW * ICT;

    int px[4], py[4];
    #pragma unroll
    for (int m = 0; m < 4; ++m) {
        int p = (pt0 + m) * 16 + colc;
        px[m] = p % OW;
        py[m] = p / OW;
    }

    f32x4 acc[4][NTW];
    if (PARTI) {
        int bimg = (n0 + n) / 81;
        const float* pp = part + (size_t)bimg * OH * OW * 96;
        #pragma unroll
        for (int m = 0; m < 4; ++m)
            #pragma unroll
            for (int nn = 0; nn < NTW; ++nn)
                #pragma unroll
                for (int j = 0; j < 4; ++j)
                    acc[m][nn][j] = pp[(size_t)((pt0 + m) * 16 + kg * 4 + j) * 96
                                       + (tile0 + nn) * 16 + colc];
    } else {
        #pragma unroll
        for (int nn = 0; nn < NTW; ++nn) {
            float bv = bias[(tile0 + nn) * 16 + colc];
            #pragma unroll
            for (int m = 0; m < 4; ++m)
                #pragma unroll
                for (int j = 0; j < 4; ++j) acc[m][nn][j] = bv;
        }
    }

    f16x8 zz = {};
    auto aload = [&](int t, int s, int m) -> f16x8 {
        int dy = t / 3 - 1, dx = t % 3 - 1;
        int sx = px[m] * S + dx, sy = py[m] * S + dy;
        bool ok = ((unsigned)sx < (unsigned)IW) && ((unsigned)sy < (unsigned)IH);
        int sxc = min(max(sx, 0), IW - 1), syc = min(max(sy, 0), IH - 1);
        f16x8 v = *(const f16x8*)(inn + ((size_t)syc * IW + sxc) * ICT + kg * 8 + s * 32);
        return ok ? v : zz;
    };
    auto bload = [&](int t, int s, int nn) -> f16x8 {
        return *(const f16x8*)(wfrag + (((t * ICS + s) * NT + tile0 + nn) << 9) + lane * 8);
    };

    // prologue: step u=0
    f16x8 aCur[4], bCur[NTW];
    #pragma unroll
    for (int m = 0; m < 4; ++m) aCur[m] = aload(0, 0, m);
    #pragma unroll
    for (int nn = 0; nn < NTW; ++nn) bCur[nn] = bload(0, 0, nn);

    #pragma unroll
    for (int u = 0; u < NU; ++u) {
        f16x8 aNxt[4], bNxt[NTW];
        if (u + 1 < NU) {
            int tn = (u + 1) / ICS, sn = (u + 1) % ICS;
            #pragma unroll
            for (int m = 0; m < 4; ++m) aNxt[m] = aload(tn, sn, m);
            #pragma unroll
            for (int nn = 0; nn < NTW; ++nn) bNxt[nn] = bload(tn, sn, nn);
        }
        #pragma unroll
        for (int m = 0; m < 4; ++m)
            #pragma unroll
            for (int nn = 0; nn < NTW; ++nn)
                acc[m][nn] = __builtin_amdgcn_mfma_f32_16x16x32_f16(aCur[m], bCur[nn], acc[m][nn], 0, 0, 0);
        if (u + 1 < NU) {
            #pragma unroll
            for (int m = 0; m < 4; ++m) aCur[m] = aNxt[m];
            #pragma unroll
            for (int nn = 0; nn < NTW; ++nn) bCur[nn] = bNxt[nn];
        }
    }

    #pragma unroll
    for (int m = 0; m < 4; ++m)
        #pragma unroll
        for (int nn = 0; nn < NTW; ++nn)
            #pragma unroll
            for (int j = 0; j < 4; ++j) {
                float r = fmaxf(acc[m][nn][j], 0.f);
                int p = (pt0 + m) * 16 + kg * 4 + j;
                out[((size_t)n * OH * OW + p) * OC + (tile0 + nn) * 16 + colc] = (half_t)r;
            }
}

// ---------------- MFMA deconv (4 parity classes), XCD-swizzled --------------
__global__ __launch_bounds__(256)
void deconv_mfma(const half_t* __restrict__ in, const half_t* __restrict__ wfrag,
                 const float* __restrict__ bias, half_t* __restrict__ out, int nb)
{
    int lb = xcd_swz(blockIdx.x, nb);
    int n = lb / 12;
    int rem = lb - n * 12;
    int cls = rem / 3;
    int tx = rem - cls * 3;

    int lane = threadIdx.x & 63;
    int wv = threadIdx.x >> 6;
    int p = cls >> 1, q = cls & 1;
    int pt0 = tx * 16 + wv * 4;
    int colc = lane & 15, kg = lane >> 4;
    const half_t* inn = in + (size_t)n * HW2 * 64;

    int pa[4], pb[4];
    #pragma unroll
    for (int m = 0; m < 4; ++m) {
        int pos = (pt0 + m) * 16 + colc;
        pa[m] = pos >> 5;
        pb[m] = pos & 31;
    }

    f32x4 acc[4][2];
    float b0 = bias[colc], b1 = bias[16 + colc];
    #pragma unroll
    for (int m = 0; m < 4; ++m)
        #pragma unroll
        for (int j = 0; j < 4; ++j) { acc[m][0][j] = b0; acc[m][1][j] = b1; }

    f16x8 zz = {};
    #pragma unroll
    for (int uv = 0; uv < 4; ++uv) {
        int u = uv >> 1, v = uv & 1;
        const half_t* ap[4];
        bool av[4];
        #pragma unroll
        for (int m = 0; m < 4; ++m) {
            int sy = pa[m] + p - 1 + u, sx = pb[m] + q - 1 + v;
            av[m] = ((unsigned)sx < (unsigned)W2) && ((unsigned)sy < (unsigned)H2);
            int sxc = min(max(sx, 0), W2 - 1), syc = min(max(sy, 0), H2 - 1);
            ap[m] = inn + ((size_t)syc * W2 + sxc) * 64 + kg * 8;
        }
        #pragma unroll
        for (int s = 0; s < 2; ++s) {
            f16x8 b0v = *(const f16x8*)(wfrag + (((cls * 8 + uv * 2 + s) * 2 + 0) << 9) + lane * 8);
            f16x8 b1v = *(const f16x8*)(wfrag + (((cls * 8 + uv * 2 + s) * 2 + 1) << 9) + lane * 8);
            #pragma unroll
            for (int m = 0; m < 4; ++m) {
                f16x8 a = *(const f16x8*)(ap[m] + s * 32);
                a = av[m] ? a : zz;
                acc[m][0] = __builtin_amdgcn_mfma_f32_16x16x32_f16(a, b0v, acc[m][0], 0, 0, 0);
                acc[m][1] = __builtin_amdgcn_mfma_f32_16x16x32_f16(a, b1v, acc[m][1], 0, 0, 0);
            }
        }
    }

    #pragma unroll
    for (int m = 0; m < 4; ++m)
        #pragma unroll
        for (int nn = 0; nn < 2; ++nn)
            #pragma unroll
            for (int j = 0; j < 4; ++j) {
                int pos = (pt0 + m) * 16 + kg * 4 + j;
                int a2 = pos >> 5, b2 = pos & 31;
                int oy = 2 * a2 + p, ox = 2 * b2 + q;
                float r = fmaxf(acc[m][nn][j], 0.f);
                out[((size_t)n * HW + oy * WW + ox) * 32 + nn * 16 + colc] = (half_t)r;
            }
}

// ---------------- conv6 (32->1), vectorized fp16 reads ----------------
__global__ void conv6_kernel(const half_t* __restrict__ in, const float* __restrict__ w6,
                             const float* __restrict__ b6, float* __restrict__ cost,
                             int n0, int nimg)
{
    int idx = blockIdx.x * blockDim.x + threadIdx.x;
    if (idx >= nimg * HW) return;
    int x = idx % WW;
    int t = idx / WW;
    int y = t % HH;
    int nl = t / HH;
    float acc = b6[0];
    const half_t* ib = in + (size_t)nl * HW * 32;
    #pragma unroll
    for (int tap = 0; tap < 9; ++tap) {
        int sy = y + tap / 3 - 1, sx = x + tap % 3 - 1;
        if ((unsigned)sy < (unsigned)HH && (unsigned)sx < (unsigned)WW) {
            const f16x8* pp = (const f16x8*)(ib + ((size_t)sy * WW + sx) * 32);
            #pragma unroll
            for (int c8 = 0; c8 < 4; ++c8) {
                f16x8 v = pp[c8];
                #pragma unroll
                for (int j = 0; j < 8; ++j)
                    acc = fmaf((float)v[j], w6[(c8 * 8 + j) * 9 + tap], acc);
            }
        }
    }
    cost[(size_t)(n0 + nl) * HW + y * WW + x] = acc;
}

// ---------------- DAP ----------------
__global__ void dap_kernel(const float* __restrict__ cost, const float* __restrict__ dapw,
                           float* __restrict__ out, int lvl)
{
    int idx = blockIdx.x * blockDim.x + threadIdx.x;
    if (idx >= NB * 81 * HW) return;
    int px = idx % HW;
    int t = idx / HW;
    int o = t % 81;
    int b = t / 81;
    const float* dw = dapw + (size_t)o * 81;
    const float* cb = cost + (size_t)b * 81 * HW + px;
    float acc = 0.f;
    #pragma unroll 9
    for (int c = 0; c < 81; ++c) acc = fmaf(dw[c], cb[(size_t)c * HW], acc);
    out[((size_t)(b * 4 * 81 + lvl * 81 + o)) * HW + px] = acc;
}

// ---------------------------------------------------------------------------
extern "C" void kernel_launch(void* const* d_in, const int* in_sizes, int n_in,
                              void* d_out, int out_size, void* d_ws, size_t ws_size,
                              hipStream_t stream)
{
    const float* f1[4] = {(const float*)d_in[0], (const float*)d_in[2],
                          (const float*)d_in[4], (const float*)d_in[6]};
    const float* f2[4] = {(const float*)d_in[1], (const float*)d_in[3],
                          (const float*)d_in[5], (const float*)d_in[7]};
    const float* coords = (const float*)d_in[8];
    const float* mw1 = (const float*)d_in[9];
    const float* mb1 = (const float*)d_in[10];
    const float* mw2 = (const float*)d_in[11];
    const float* mb2 = (const float*)d_in[12];
    const float* mw3 = (const float*)d_in[13];
    const float* mb3 = (const float*)d_in[14];
    const float* mw4 = (const float*)d_in[15];
    const float* mb4 = (const float*)d_in[16];
    const float* mw5 = (const float*)d_in[17];
    const float* mb5 = (const float*)d_in[18];
    const float* mw6 = (const float*)d_in[19];
    const float* mb6 = (const float*)d_in[20];
    const float* dapw = (const float*)d_in[21];
    float* out = (float*)d_out;

    auto al = [](size_t x) { return (x + 255) / 256 * 256; };
    const size_t wT1B = al((size_t)4 * WT1L * 4);
    const size_t fragB = al((size_t)4 * (F1S + F2S + F3S + F4S + F5S) * 2);
    const size_t partB = al((size_t)NB * HW * 96 * 4);
    const size_t costB = al((size_t)NIMG * HW * 4);
    const size_t SA = (size_t)HW * 32 * 2;
    const size_t SB = (size_t)HW * 96 * 2;

    static const int divs[10] = {162, 81, 54, 27, 18, 9, 6, 3, 2, 1};
    int chunk = 1;
    for (int i = 0; i < 10; ++i) {
        size_t need = wT1B + fragB + partB + costB + (size_t)divs[i] * (SA + SB) + 1024;
        if (need <= ws_size) { chunk = divs[i]; break; }
    }

    char* wsb = (char*)d_ws;
    float* wT1 = (float*)wsb;
    half_t* frags = (half_t*)(wsb + wT1B);
    half_t* Fr1 = frags;
    half_t* Fr2 = Fr1 + (size_t)4 * F1S;
    half_t* Fr3 = Fr2 + (size_t)4 * F2S;
    half_t* Fr4 = Fr3 + (size_t)4 * F3S;
    half_t* Fr5 = Fr4 + (size_t)4 * F4S;
    float* part = (float*)(wsb + wT1B + fragB);
    float* cost = (float*)(wsb + wT1B + fragB + partB);
    half_t* bufA = (half_t*)(wsb + wT1B + fragB + partB + costB);
    half_t* bufB = (half_t*)(wsb + wT1B + fragB + partB + costB + (size_t)chunk * SA);

    const int TPB = 256;

    transpose_w<<<cdiv(4 * 96 * KT1, TPB), TPB, 0, stream>>>(mw1, wT1, 96, KT1, WT1L);
    prep3<96, 64, 32, 1><<<cdiv(4 * F1S, TPB), TPB, 0, stream>>>(mw1, Fr1);
    prep3<128, 96, 0, 3><<<cdiv(4 * F2S, TPB), TPB, 0, stream>>>(mw2, Fr2);
    prep3<128, 128, 0, 4><<<cdiv(4 * F3S, TPB), TPB, 0, stream>>>(mw3, Fr3);
    prep3<64, 128, 0, 4><<<cdiv(4 * F4S, TPB), TPB, 0, stream>>>(mw4, Fr4);
    prep5<<<cdiv(4 * F5S, TPB), TPB, 0, stream>>>(mw5, Fr5);

    for (int lvl = 0; lvl < 4; ++lvl) {
        int h2 = HH >> lvl, w2 = WW >> lvl;
        float inv_scale = 1.0f / (float)(1 << lvl);
        const float* b1 = mb1 + (size_t)lvl * 96;
        const float* b2 = mb2 + (size_t)lvl * 128;
        const float* b3 = mb3 + (size_t)lvl * 128;
        const float* b4 = mb4 + (size_t)lvl * 64;
        const float* b5 = mb5 + (size_t)lvl * 32;
        const float* w6 = mw6 + (size_t)lvl * 288;
        const float* b6 = mb6 + (size_t)lvl * 1;

        conv_part<<<dim3(12, 6, 2), TPB, 0, stream>>>(f1[lvl], wT1 + (size_t)lvl * WT1L, b1, part);

        for (int n0 = 0; n0 < NIMG; n0 += chunk) {
            int n = chunk;
            sample_kernel<<<cdiv(n * HW, TPB), TPB, 0, stream>>>(
                f2[lvl], coords, bufA, n0, n, h2, w2, inv_scale);
            // conv1 sampled-half MFMA + part C-init, relu: A -> B  (NT=6, NTW=3, gy=2)
            { int gx = 12, gxy = 24, nb = gxy * n;
              conv_mfma<1, 32, 96, 48, 64, 48, 64, 1, true, 3><<<nb, TPB, 0, stream>>>(
                  bufA, Fr1 + (size_t)lvl * F1S, b1, bufB, part, n0, gx, gxy, nb); }
            // conv2 96->128 s2 relu: B -> A  (NT=8, NTW=4, gy=2)
            { int gx = 3, gxy = 6, nb = gxy * n;
              conv_mfma<3, 96, 128, 48, 64, 24, 32, 2, false, 4><<<nb, TPB, 0, stream>>>(
                  bufB, Fr2 + (size_t)lvl * F2S, b2, bufA, nullptr, 0, gx, gxy, nb); }
            // conv3 128->128 relu: A -> B  (NT=8, NTW=4, gy=2)
            { int gx = 3, gxy = 6, nb = gxy * n;
              conv_mfma<4, 128, 128, 24, 32, 24, 32, 1, false, 4><<<nb, TPB, 0, stream>>>(
                  bufA, Fr3 + (size_t)lvl * F3S, b3, bufB, nullptr, 0, gx, gxy, nb); }
            // conv4 128->64 relu: B -> A  (NT=4, NTW=4, gy=1)
            { int gx = 3, gxy = 3, nb = gxy * n;
              conv_mfma<4, 128, 64, 24, 32, 24, 32, 1, false, 4><<<nb, TPB, 0, stream>>>(
                  bufB, Fr4 + (size_t)lvl * F4S, b4, bufA, nullptr, 0, gx, gxy, nb); }
            // deconv 64->32 relu: A -> B
            { int nb = 12 * n;
              deconv_mfma<<<nb, TPB, 0, stream>>>(bufA, Fr5 + (size_t)lvl * F5S, b5, bufB, nb); }
            // conv6 32->1: B -> cost
            conv6_kernel<<<cdiv(n * HW, TPB), TPB, 0, stream>>>(bufB, w6, b6, cost, n0, n);
        }
        dap_kernel<<<cdiv(NB * 81 * HW, TPB), TPB, 0, stream>>>(
            cost, dapw + (size_t)lvl * 81 * 81, out, lvl);
    }
}